// Round 2
// baseline (1755.001 us; speedup 1.0000x reference)
//
#include <hip/hip_runtime.h>
#include <hip/hip_bf16.h>

#define B_  64
#define TX  128
#define H_  1024
#define E_  512
#define KY  32000
#define H2  2048   // 2H
#define H3  3072   // 3H
#define EC  2560   // E+2H
#define M_  (TX*B_) // 8192
#define WST 132    // LDS row stride for W tile (16B aligned, padded)

// ---------------- K1: hpart[b][h] = ab1[h] + hidden[b,:] . aW1[h, :H] ----------------
__global__ void k1_hpart(const float* __restrict__ hidden, const float* __restrict__ aW1,
                         const float* __restrict__ ab1, float* __restrict__ hpart) {
  int b = blockIdx.y;
  int wave = threadIdx.x >> 6;
  int lane = threadIdx.x & 63;
  int h = blockIdx.x * 4 + wave;
  const float* wrow = aW1 + (size_t)h * H3;
  const float* hrow = hidden + b * H_;
  float acc = 0.f;
  for (int j = 0; j < H_ / 64; ++j) {
    int i = j * 64 + lane;
    acc += hrow[i] * wrow[i];
  }
  for (int off = 32; off; off >>= 1) acc += __shfl_down(acc, off);
  if (lane == 0) hpart[b * H_ + h] = acc + ab1[h];
}

// ---------------- K2: big GEMM (8192x2048 @ 2048x1024) + tanh + aW2-reduce ----------------
__global__ __launch_bounds__(256) void k2_gemm_score(
    const float* __restrict__ enc, const float* __restrict__ aW1,
    const float* __restrict__ hpart, const float* __restrict__ aW2,
    float* __restrict__ scorepart) {
  __shared__ float As[32][68];
  __shared__ float Bs[32][68];
  __shared__ float red[64][17];
  int m0 = blockIdx.x * 64;
  int n0 = blockIdx.y * 64;
  int tid = threadIdx.x;
  int ty = tid >> 4, tx = tid & 15;
  float acc[4][4] = {};
  for (int k0 = 0; k0 < H2; k0 += 32) {
    #pragma unroll
    for (int l = 0; l < 2; ++l) {
      int fi = tid + l * 256;
      int m = fi >> 3;
      int kq = (fi & 7) * 4;
      const float4 v = *(const float4*)&enc[(size_t)(m0 + m) * H2 + k0 + kq];
      As[kq + 0][m] = v.x; As[kq + 1][m] = v.y; As[kq + 2][m] = v.z; As[kq + 3][m] = v.w;
      const float4 u = *(const float4*)&aW1[(size_t)(n0 + m) * H3 + H_ + k0 + kq];
      Bs[kq + 0][m] = u.x; Bs[kq + 1][m] = u.y; Bs[kq + 2][m] = u.z; Bs[kq + 3][m] = u.w;
    }
    __syncthreads();
    #pragma unroll
    for (int kk = 0; kk < 32; ++kk) {
      float4 av = *(const float4*)&As[kk][ty * 4];
      float4 bv = *(const float4*)&Bs[kk][tx * 4];
      float a[4] = {av.x, av.y, av.z, av.w};
      float b[4] = {bv.x, bv.y, bv.z, bv.w};
      #pragma unroll
      for (int i = 0; i < 4; ++i)
        #pragma unroll
        for (int j = 0; j < 4; ++j)
          acc[i][j] += a[i] * b[j];
    }
    __syncthreads();
  }
  #pragma unroll
  for (int i = 0; i < 4; ++i) {
    int m = m0 + ty * 4 + i;
    int bb = m & 63;
    float p = 0.f;
    #pragma unroll
    for (int j = 0; j < 4; ++j) {
      int n = n0 + tx * 4 + j;
      p += aW2[n] * tanhf(hpart[bb * H_ + n] + acc[i][j]);
    }
    red[ty * 4 + i][tx] = p;
  }
  __syncthreads();
  if (tid < 64) {
    float s = 0.f;
    #pragma unroll
    for (int j = 0; j < 16; ++j) s += red[tid][j];
    scorepart[(size_t)blockIdx.y * M_ + m0 + tid] = s;
  }
}

// ---------------- K3: softmax over t (per b) ----------------
__global__ void k3_softmax(const float* __restrict__ scorepart, const float* __restrict__ ab2,
                           float* __restrict__ w) {
  int b = blockIdx.x;
  int t = threadIdx.x; // 128
  float s = ab2[0];
  for (int nb = 0; nb < 16; ++nb) s += scorepart[nb * M_ + t * B_ + b];
  __shared__ float sm[128];
  sm[t] = s; __syncthreads();
  for (int off = 64; off; off >>= 1) {
    if (t < off) sm[t] = fmaxf(sm[t], sm[t + off]);
    __syncthreads();
  }
  float mx = sm[0]; __syncthreads();
  float e = expf(s - mx);
  sm[t] = e; __syncthreads();
  for (int off = 64; off; off >>= 1) {
    if (t < off) sm[t] += sm[t + off];
    __syncthreads();
  }
  w[t * B_ + b] = e / sm[0];
}

// ---------------- K4: context[b][k] = sum_t w[t][b]*enc[t][b][k] ----------------
__global__ void k4_context(const float* __restrict__ enc, const float* __restrict__ w,
                           float* __restrict__ context) {
  int b = blockIdx.y;
  int k = blockIdx.x * 256 + threadIdx.x;
  __shared__ float wl[TX];
  if (threadIdx.x < TX) wl[threadIdx.x] = w[threadIdx.x * B_ + b];
  __syncthreads();
  float acc = 0.f;
  for (int t = 0; t < TX; ++t)
    acc += wl[t] * enc[((size_t)t * B_ + b) * H2 + k];
  context[b * H2 + k] = acc;
}

// ---------------- K5a: rnn_in = [embed, context] ----------------
__global__ void k5a_rnnin(const int* __restrict__ input, const float* __restrict__ emb_W,
                          const float* __restrict__ context, float* __restrict__ rnn_in) {
  int b = blockIdx.x;
  int tok = input[b];
  for (int c = threadIdx.x; c < EC; c += blockDim.x)
    rnn_in[b * EC + c] = (c < E_) ? emb_W[(size_t)tok * E_ + c] : context[b * H2 + (c - E_)];
}

// ---------------- small-M GEMM v2: W tile staged in LDS (coalesced), x in regs ----------------
// out[ks][b][n] = (ks==0 ? bias[n] : 0) + sum over this k-split of x[b,:].W[n,:]
// block: 256 thr = 4 waves; lane = b; wave g owns 16 n-rows. blockIdx.y = k-split.
__global__ __launch_bounds__(256) void k_gemm_T(
    const float* __restrict__ x, const float* __restrict__ W,
    const float* __restrict__ bias, float* __restrict__ out, int N, int K) {
  __shared__ float Ws[64 * WST];
  int tid = threadIdx.x;
  int b = tid & 63, g = tid >> 6;
  int n0 = blockIdx.x * 64;
  int ks = blockIdx.y;
  int kchunk = K / gridDim.y;      // multiple of 128 by construction
  int kbeg = ks * kchunk, kend = kbeg + kchunk;
  float acc[16] = {};
  const float4* xv = (const float4*)(x + (size_t)b * K);
  for (int k0 = kbeg; k0 < kend; k0 += 128) {
    __syncthreads();
    // stage W[n0..n0+63][k0..k0+127]: 2048 float4, coalesced (1 KiB/wave-instr)
    #pragma unroll
    for (int l = 0; l < 8; ++l) {
      int f = l * 256 + tid;
      int row = f >> 5, c4 = f & 31;
      float4 v = *(const float4*)&W[(size_t)(n0 + row) * K + k0 + c4 * 4];
      *(float4*)&Ws[row * WST + c4 * 4] = v;
    }
    __syncthreads();
    #pragma unroll
    for (int kb = 0; kb < 128; kb += 16) {
      float4 x0 = xv[(k0 + kb) / 4 + 0];
      float4 x1 = xv[(k0 + kb) / 4 + 1];
      float4 x2 = xv[(k0 + kb) / 4 + 2];
      float4 x3 = xv[(k0 + kb) / 4 + 3];
      #pragma unroll
      for (int i = 0; i < 16; ++i) {
        const float* wr = &Ws[(g * 16 + i) * WST + kb];   // lane-uniform -> LDS broadcast
        float4 w0 = *(const float4*)(wr + 0);
        float4 w1 = *(const float4*)(wr + 4);
        float4 w2 = *(const float4*)(wr + 8);
        float4 w3 = *(const float4*)(wr + 12);
        acc[i] += x0.x*w0.x + x0.y*w0.y + x0.z*w0.z + x0.w*w0.w
                + x1.x*w1.x + x1.y*w1.y + x1.z*w1.z + x1.w*w1.w
                + x2.x*w2.x + x2.y*w2.y + x2.z*w2.z + x2.w*w2.w
                + x3.x*w3.x + x3.y*w3.y + x3.z*w3.z + x3.w*w3.w;
      }
    }
  }
  float* po = out + (size_t)ks * 64 * N;
  #pragma unroll
  for (int i = 0; i < 16; ++i) {
    int n = n0 + g * 16 + i;
    float v = acc[i];
    if (ks == 0) v += bias[n];
    po[(size_t)b * N + n] = v;
  }
}

// ---------------- K5c: sum k-split partials -> GRU gates + xcat = [h_new, context] ----------------
__global__ void k5c_gates(const float* __restrict__ gip, const float* __restrict__ ghp,
                          int gis, int ghs,
                          const float* __restrict__ hidden, const float* __restrict__ context,
                          float* __restrict__ hnew_out, float* __restrict__ xcat) {
  int b = blockIdx.x;
  for (int h = threadIdx.x; h < H_; h += blockDim.x) {
    float ir = 0.f, iz = 0.f, inn = 0.f;
    for (int s = 0; s < gis; ++s) {
      const float* gb = gip + (size_t)s * B_ * H3 + (size_t)b * H3;
      ir += gb[h]; iz += gb[H_ + h]; inn += gb[H2 + h];
    }
    float hr = 0.f, hz = 0.f, hn = 0.f;
    for (int s = 0; s < ghs; ++s) {
      const float* gb = ghp + (size_t)s * B_ * H3 + (size_t)b * H3;
      hr += gb[h]; hz += gb[H_ + h]; hn += gb[H2 + h];
    }
    float r = 1.f / (1.f + expf(-(ir + hr)));
    float z = 1.f / (1.f + expf(-(iz + hz)));
    float n = tanhf(inn + r * hn);
    float hv = hidden[b * H_ + h];
    float hnew = (1.f - z) * n + z * hv;
    hnew_out[b * H_ + h] = hnew;
    xcat[b * H3 + h] = hnew;
  }
  for (int c = threadIdx.x; c < H2; c += blockDim.x)
    xcat[b * H3 + H_ + c] = context[b * H2 + c];
}

// ---------------- K7: per-row logsumexp of logits ----------------
__global__ void k7_lse(const float* __restrict__ logits, float* __restrict__ lse) {
  int b = blockIdx.x;
  const float* row = logits + (size_t)b * KY;
  __shared__ float sm[256];
  float mx = -1e30f;
  for (int k = threadIdx.x; k < KY; k += 256) mx = fmaxf(mx, row[k]);
  sm[threadIdx.x] = mx; __syncthreads();
  for (int off = 128; off; off >>= 1) {
    if (threadIdx.x < off) sm[threadIdx.x] = fmaxf(sm[threadIdx.x], sm[threadIdx.x + off]);
    __syncthreads();
  }
  mx = sm[0]; __syncthreads();
  float s = 0.f;
  for (int k = threadIdx.x; k < KY; k += 256) s += expf(row[k] - mx);
  sm[threadIdx.x] = s; __syncthreads();
  for (int off = 128; off; off >>= 1) {
    if (threadIdx.x < off) sm[threadIdx.x] += sm[threadIdx.x + off];
    __syncthreads();
  }
  if (threadIdx.x == 0) lse[b] = mx + logf(sm[0]);
}

// ---------------- K8: in-place out = logits - lse ----------------
__global__ void k8_out(float* __restrict__ outp, const float* __restrict__ lse) {
  int b = blockIdx.y;
  int k = blockIdx.x * 256 + threadIdx.x;
  size_t idx = (size_t)b * KY + k;
  outp[idx] = outp[idx] - lse[b];
}

extern "C" void kernel_launch(void* const* d_in, const int* in_sizes, int n_in,
                              void* d_out, int out_size, void* d_ws, size_t ws_size,
                              hipStream_t stream) {
  const int*   input  = (const int*)  d_in[0];
  const float* hidden = (const float*)d_in[1];
  const float* enc    = (const float*)d_in[2];
  const float* emb_W  = (const float*)d_in[3];
  const float* Wih    = (const float*)d_in[4];
  const float* Whh    = (const float*)d_in[5];
  const float* bih    = (const float*)d_in[6];
  const float* bhh    = (const float*)d_in[7];
  const float* lsm_W  = (const float*)d_in[8];
  const float* lsm_b  = (const float*)d_in[9];
  const float* aW1    = (const float*)d_in[10];
  const float* ab1    = (const float*)d_in[11];
  const float* aW2    = (const float*)d_in[12];
  const float* ab2    = (const float*)d_in[13];

  float* out   = (float*)d_out;           // log_softmax output (logits in place first)
  float* hnew  = out + (size_t)B_ * KY;   // h_new

  // k-splits for the two gate GEMMs (chunks must be multiples of 128):
  // gi: K=2560 -> 5 x 512 ; gh: K=1024 -> 2 x 512. Fallback to 1 if ws too small.
  int gis = 5, ghs = 2;
  size_t need = (size_t)(65536 + 131072 + 8192 + 131072 + 163840
                         + gis * 196608 + ghs * 196608 + 196608 + 64) * 4;
  if (ws_size < need) { gis = 1; ghs = 1; }

  float* ws = (float*)d_ws;
  float* hpart     = ws;                         // 64*1024
  float* scorepart = hpart + 65536;              // 16*8192
  float* w         = scorepart + 131072;         // 8192
  float* context   = w + 8192;                   // 64*2048
  float* rnn_in    = context + 131072;           // 64*2560
  float* gi        = rnn_in + 163840;            // gis*64*3072
  float* gh        = gi + (size_t)gis * 196608;  // ghs*64*3072
  float* xcat      = gh + (size_t)ghs * 196608;  // 64*3072
  float* lse       = xcat + 196608;              // 64

  k1_hpart<<<dim3(256, 64), 256, 0, stream>>>(hidden, aW1, ab1, hpart);
  k2_gemm_score<<<dim3(M_ / 64, 16), 256, 0, stream>>>(enc, aW1, hpart, aW2, scorepart);
  k3_softmax<<<B_, TX, 0, stream>>>(scorepart, ab2, w);
  k4_context<<<dim3(H2 / 256, B_), 256, 0, stream>>>(enc, w, context);
  k5a_rnnin<<<B_, 256, 0, stream>>>(input, emb_W, context, rnn_in);
  k_gemm_T<<<dim3(H3 / 64, gis), 256, 0, stream>>>(rnn_in, Wih, bih, gi, H3, EC);
  k_gemm_T<<<dim3(H3 / 64, ghs), 256, 0, stream>>>(hidden, Whh, bhh, gh, H3, H_);
  k5c_gates<<<B_, 256, 0, stream>>>(gi, gh, gis, ghs, hidden, context, hnew, xcat);
  k_gemm_T<<<dim3(KY / 64, 1), 256, 0, stream>>>(xcat, lsm_W, lsm_b, out, KY, H3);
  k7_lse<<<B_, 256, 0, stream>>>(out, lse);
  k8_out<<<dim3(KY / 256, B_), 256, 0, stream>>>(out, lse);
}

// Round 3
// 899.433 us; speedup vs baseline: 1.9512x; 1.9512x over previous
//
#include <hip/hip_runtime.h>
#include <hip/hip_bf16.h>

#define B_  64
#define TX  128
#define H_  1024
#define E_  512
#define KY  32000
#define H2  2048   // 2H
#define H3  3072   // 3H
#define EC  2560   // E+2H
#define M_  (TX*B_) // 8192
#define WST 132    // LDS row stride for W tile (16B aligned, padded)

typedef __bf16 bf16x8 __attribute__((ext_vector_type(8)));
typedef unsigned short u16x8 __attribute__((ext_vector_type(8)));
typedef float f32x4 __attribute__((ext_vector_type(4)));

// f32 -> bf16 round-to-nearest-even (no NaN path needed for this data)
__device__ __forceinline__ unsigned short f2bf(float f) {
  unsigned int u = __builtin_bit_cast(unsigned int, f);
  u += 0x7fff + ((u >> 16) & 1);
  return (unsigned short)(u >> 16);
}

// ---------------- K1: hpart[b][h] = ab1[h] + hidden[b,:] . aW1[h, :H] ----------------
__global__ void k1_hpart(const float* __restrict__ hidden, const float* __restrict__ aW1,
                         const float* __restrict__ ab1, float* __restrict__ hpart) {
  int b = blockIdx.y;
  int wave = threadIdx.x >> 6;
  int lane = threadIdx.x & 63;
  int h = blockIdx.x * 4 + wave;
  const float* wrow = aW1 + (size_t)h * H3;
  const float* hrow = hidden + b * H_;
  float acc = 0.f;
  for (int j = 0; j < H_ / 64; ++j) {
    int i = j * 64 + lane;
    acc += hrow[i] * wrow[i];
  }
  for (int off = 32; off; off >>= 1) acc += __shfl_down(acc, off);
  if (lane == 0) hpart[b * H_ + h] = acc + ab1[h];
}

// ---------------- K2: big GEMM (8192x2048 @ 2048x1024) + tanh + aW2-reduce ----------------
__global__ __launch_bounds__(256) void k2_gemm_score(
    const float* __restrict__ enc, const float* __restrict__ aW1,
    const float* __restrict__ hpart, const float* __restrict__ aW2,
    float* __restrict__ scorepart) {
  __shared__ float As[32][68];
  __shared__ float Bs[32][68];
  __shared__ float red[64][17];
  int m0 = blockIdx.x * 64;
  int n0 = blockIdx.y * 64;
  int tid = threadIdx.x;
  int ty = tid >> 4, tx = tid & 15;
  float acc[4][4] = {};
  for (int k0 = 0; k0 < H2; k0 += 32) {
    #pragma unroll
    for (int l = 0; l < 2; ++l) {
      int fi = tid + l * 256;
      int m = fi >> 3;
      int kq = (fi & 7) * 4;
      const float4 v = *(const float4*)&enc[(size_t)(m0 + m) * H2 + k0 + kq];
      As[kq + 0][m] = v.x; As[kq + 1][m] = v.y; As[kq + 2][m] = v.z; As[kq + 3][m] = v.w;
      const float4 u = *(const float4*)&aW1[(size_t)(n0 + m) * H3 + H_ + k0 + kq];
      Bs[kq + 0][m] = u.x; Bs[kq + 1][m] = u.y; Bs[kq + 2][m] = u.z; Bs[kq + 3][m] = u.w;
    }
    __syncthreads();
    #pragma unroll
    for (int kk = 0; kk < 32; ++kk) {
      float4 av = *(const float4*)&As[kk][ty * 4];
      float4 bv = *(const float4*)&Bs[kk][tx * 4];
      float a[4] = {av.x, av.y, av.z, av.w};
      float b[4] = {bv.x, bv.y, bv.z, bv.w};
      #pragma unroll
      for (int i = 0; i < 4; ++i)
        #pragma unroll
        for (int j = 0; j < 4; ++j)
          acc[i][j] += a[i] * b[j];
    }
    __syncthreads();
  }
  #pragma unroll
  for (int i = 0; i < 4; ++i) {
    int m = m0 + ty * 4 + i;
    int bb = m & 63;
    float p = 0.f;
    #pragma unroll
    for (int j = 0; j < 4; ++j) {
      int n = n0 + tx * 4 + j;
      p += aW2[n] * tanhf(hpart[bb * H_ + n] + acc[i][j]);
    }
    red[ty * 4 + i][tx] = p;
  }
  __syncthreads();
  if (tid < 64) {
    float s = 0.f;
    #pragma unroll
    for (int j = 0; j < 16; ++j) s += red[tid][j];
    scorepart[(size_t)blockIdx.y * M_ + m0 + tid] = s;
  }
}

// ---------------- K3: softmax over t (per b) ----------------
__global__ void k3_softmax(const float* __restrict__ scorepart, const float* __restrict__ ab2,
                           float* __restrict__ w) {
  int b = blockIdx.x;
  int t = threadIdx.x; // 128
  float s = ab2[0];
  for (int nb = 0; nb < 16; ++nb) s += scorepart[nb * M_ + t * B_ + b];
  __shared__ float sm[128];
  sm[t] = s; __syncthreads();
  for (int off = 64; off; off >>= 1) {
    if (t < off) sm[t] = fmaxf(sm[t], sm[t + off]);
    __syncthreads();
  }
  float mx = sm[0]; __syncthreads();
  float e = expf(s - mx);
  sm[t] = e; __syncthreads();
  for (int off = 64; off; off >>= 1) {
    if (t < off) sm[t] += sm[t + off];
    __syncthreads();
  }
  w[t * B_ + b] = e / sm[0];
}

// ---------------- K4: context[b][k] = sum_t w[t][b]*enc[t][b][k] ----------------
__global__ void k4_context(const float* __restrict__ enc, const float* __restrict__ w,
                           float* __restrict__ context) {
  int b = blockIdx.y;
  int k = blockIdx.x * 256 + threadIdx.x;
  __shared__ float wl[TX];
  if (threadIdx.x < TX) wl[threadIdx.x] = w[threadIdx.x * B_ + b];
  __syncthreads();
  float acc = 0.f;
  for (int t = 0; t < TX; ++t)
    acc += wl[t] * enc[((size_t)t * B_ + b) * H2 + k];
  context[b * H2 + k] = acc;
}

// ---------------- K5a: rnn_in = [embed, context] ----------------
__global__ void k5a_rnnin(const int* __restrict__ input, const float* __restrict__ emb_W,
                          const float* __restrict__ context, float* __restrict__ rnn_in) {
  int b = blockIdx.x;
  int tok = input[b];
  for (int c = threadIdx.x; c < EC; c += blockDim.x)
    rnn_in[b * EC + c] = (c < E_) ? emb_W[(size_t)tok * E_ + c] : context[b * H2 + (c - E_)];
}

// ---------------- small-M GEMM (gi/gh): W tile staged in LDS, x in regs ----------------
__global__ __launch_bounds__(256) void k_gemm_T(
    const float* __restrict__ x, const float* __restrict__ W,
    const float* __restrict__ bias, float* __restrict__ out, int N, int K) {
  __shared__ float Ws[64 * WST];
  int tid = threadIdx.x;
  int b = tid & 63, g = tid >> 6;
  int n0 = blockIdx.x * 64;
  int ks = blockIdx.y;
  int kchunk = K / gridDim.y;
  int kbeg = ks * kchunk, kend = kbeg + kchunk;
  float acc[16] = {};
  const float4* xv = (const float4*)(x + (size_t)b * K);
  for (int k0 = kbeg; k0 < kend; k0 += 128) {
    __syncthreads();
    #pragma unroll
    for (int l = 0; l < 8; ++l) {
      int f = l * 256 + tid;
      int row = f >> 5, c4 = f & 31;
      float4 v = *(const float4*)&W[(size_t)(n0 + row) * K + k0 + c4 * 4];
      *(float4*)&Ws[row * WST + c4 * 4] = v;
    }
    __syncthreads();
    #pragma unroll
    for (int kb = 0; kb < 128; kb += 16) {
      float4 x0 = xv[(k0 + kb) / 4 + 0];
      float4 x1 = xv[(k0 + kb) / 4 + 1];
      float4 x2 = xv[(k0 + kb) / 4 + 2];
      float4 x3 = xv[(k0 + kb) / 4 + 3];
      #pragma unroll
      for (int i = 0; i < 16; ++i) {
        const float* wr = &Ws[(g * 16 + i) * WST + kb];
        float4 w0 = *(const float4*)(wr + 0);
        float4 w1 = *(const float4*)(wr + 4);
        float4 w2 = *(const float4*)(wr + 8);
        float4 w3 = *(const float4*)(wr + 12);
        acc[i] += x0.x*w0.x + x0.y*w0.y + x0.z*w0.z + x0.w*w0.w
                + x1.x*w1.x + x1.y*w1.y + x1.z*w1.z + x1.w*w1.w
                + x2.x*w2.x + x2.y*w2.y + x2.z*w2.z + x2.w*w2.w
                + x3.x*w3.x + x3.y*w3.y + x3.z*w3.z + x3.w*w3.w;
      }
    }
  }
  float* po = out + (size_t)ks * 64 * N;
  #pragma unroll
  for (int i = 0; i < 16; ++i) {
    int n = n0 + g * 16 + i;
    float v = acc[i];
    if (ks == 0) v += bias[n];
    po[(size_t)b * N + n] = v;
  }
}

// ---------------- K5c: k-split partials -> GRU gates; writes hnew + xb (bf16 [h_new,context]) ----------------
__global__ void k5c_gates(const float* __restrict__ gip, const float* __restrict__ ghp,
                          int gis, int ghs,
                          const float* __restrict__ hidden, const float* __restrict__ context,
                          float* __restrict__ hnew_out, unsigned short* __restrict__ xb) {
  int b = blockIdx.x;
  for (int h = threadIdx.x; h < H_; h += blockDim.x) {
    float ir = 0.f, iz = 0.f, inn = 0.f;
    for (int s = 0; s < gis; ++s) {
      const float* gb = gip + (size_t)s * B_ * H3 + (size_t)b * H3;
      ir += gb[h]; iz += gb[H_ + h]; inn += gb[H2 + h];
    }
    float hr = 0.f, hz = 0.f, hn = 0.f;
    for (int s = 0; s < ghs; ++s) {
      const float* gb = ghp + (size_t)s * B_ * H3 + (size_t)b * H3;
      hr += gb[h]; hz += gb[H_ + h]; hn += gb[H2 + h];
    }
    float r = 1.f / (1.f + expf(-(ir + hr)));
    float z = 1.f / (1.f + expf(-(iz + hz)));
    float n = tanhf(inn + r * hn);
    float hv = hidden[b * H_ + h];
    float hnew = (1.f - z) * n + z * hv;
    hnew_out[b * H_ + h] = hnew;
    xb[b * H3 + h] = f2bf(hnew);
  }
  for (int c = threadIdx.x; c < H2; c += blockDim.x)
    xb[b * H3 + H_ + c] = f2bf(context[b * H2 + c]);
}

// ---------------- K6: lsm logits via bf16 MFMA, W converted on the fly ----------------
// out[b][n] = bias[n] + xb[b,:] . bf16(W[n,:]);  grid = KY/64 blocks, 4 waves each.
// Wave wv owns n-cols [n0+wv*16, +16); all 64 b rows via 4 A-fragments (read from L2).
__global__ __launch_bounds__(256) void k6_lsm_mfma(
    const unsigned short* __restrict__ xb, const float* __restrict__ W,
    const float* __restrict__ bias, float* __restrict__ out) {
  int tid = threadIdx.x;
  int wv = tid >> 6, lane = tid & 63;
  int n = blockIdx.x * 64 + wv * 16 + (lane & 15);
  int kg = lane >> 4;                      // 0..3: which 8-wide k-group
  const float* wp = W + (size_t)n * H3 + kg * 8;
  const unsigned short* xp = xb + (size_t)(lane & 15) * H3 + kg * 8;
  f32x4 a0 = {0.f, 0.f, 0.f, 0.f}, a1 = a0, a2 = a0, a3 = a0;
  #pragma unroll 2
  for (int k0 = 0; k0 < H3; k0 += 32) {
    float4 wlo = *(const float4*)(wp + k0);
    float4 whi = *(const float4*)(wp + k0 + 4);
    u16x8 bu;
    bu[0] = f2bf(wlo.x); bu[1] = f2bf(wlo.y); bu[2] = f2bf(wlo.z); bu[3] = f2bf(wlo.w);
    bu[4] = f2bf(whi.x); bu[5] = f2bf(whi.y); bu[6] = f2bf(whi.z); bu[7] = f2bf(whi.w);
    bf16x8 bf = __builtin_bit_cast(bf16x8, bu);
    u16x8 x0 = *(const u16x8*)(xp + k0);
    u16x8 x1 = *(const u16x8*)(xp + 16 * H3 + k0);
    u16x8 x2 = *(const u16x8*)(xp + 32 * H3 + k0);
    u16x8 x3 = *(const u16x8*)(xp + 48 * H3 + k0);
    a0 = __builtin_amdgcn_mfma_f32_16x16x32_bf16(__builtin_bit_cast(bf16x8, x0), bf, a0, 0, 0, 0);
    a1 = __builtin_amdgcn_mfma_f32_16x16x32_bf16(__builtin_bit_cast(bf16x8, x1), bf, a1, 0, 0, 0);
    a2 = __builtin_amdgcn_mfma_f32_16x16x32_bf16(__builtin_bit_cast(bf16x8, x2), bf, a2, 0, 0, 0);
    a3 = __builtin_amdgcn_mfma_f32_16x16x32_bf16(__builtin_bit_cast(bf16x8, x3), bf, a3, 0, 0, 0);
  }
  float bv = bias[n];
  int r0 = kg * 4;                          // C/D: row = (lane>>4)*4 + reg, col = lane&15
  #pragma unroll
  for (int r = 0; r < 4; ++r) {
    out[(size_t)(r0 + r) * KY + n]      = a0[r] + bv;
    out[(size_t)(16 + r0 + r) * KY + n] = a1[r] + bv;
    out[(size_t)(32 + r0 + r) * KY + n] = a2[r] + bv;
    out[(size_t)(48 + r0 + r) * KY + n] = a3[r] + bv;
  }
}

// ---------------- K7: per-row logsumexp of logits ----------------
__global__ void k7_lse(const float* __restrict__ logits, float* __restrict__ lse) {
  int b = blockIdx.x;
  const float* row = logits + (size_t)b * KY;
  __shared__ float sm[256];
  float mx = -1e30f;
  for (int k = threadIdx.x; k < KY; k += 256) mx = fmaxf(mx, row[k]);
  sm[threadIdx.x] = mx; __syncthreads();
  for (int off = 128; off; off >>= 1) {
    if (threadIdx.x < off) sm[threadIdx.x] = fmaxf(sm[threadIdx.x], sm[threadIdx.x + off]);
    __syncthreads();
  }
  mx = sm[0]; __syncthreads();
  float s = 0.f;
  for (int k = threadIdx.x; k < KY; k += 256) s += expf(row[k] - mx);
  sm[threadIdx.x] = s; __syncthreads();
  for (int off = 128; off; off >>= 1) {
    if (threadIdx.x < off) sm[threadIdx.x] += sm[threadIdx.x + off];
    __syncthreads();
  }
  if (threadIdx.x == 0) lse[b] = mx + logf(sm[0]);
}

// ---------------- K8: in-place out = logits - lse ----------------
__global__ void k8_out(float* __restrict__ outp, const float* __restrict__ lse) {
  int b = blockIdx.y;
  int k = blockIdx.x * 256 + threadIdx.x;
  size_t idx = (size_t)b * KY + k;
  outp[idx] = outp[idx] - lse[b];
}

extern "C" void kernel_launch(void* const* d_in, const int* in_sizes, int n_in,
                              void* d_out, int out_size, void* d_ws, size_t ws_size,
                              hipStream_t stream) {
  const int*   input  = (const int*)  d_in[0];
  const float* hidden = (const float*)d_in[1];
  const float* enc    = (const float*)d_in[2];
  const float* emb_W  = (const float*)d_in[3];
  const float* Wih    = (const float*)d_in[4];
  const float* Whh    = (const float*)d_in[5];
  const float* bih    = (const float*)d_in[6];
  const float* bhh    = (const float*)d_in[7];
  const float* lsm_W  = (const float*)d_in[8];
  const float* lsm_b  = (const float*)d_in[9];
  const float* aW1    = (const float*)d_in[10];
  const float* ab1    = (const float*)d_in[11];
  const float* aW2    = (const float*)d_in[12];
  const float* ab2    = (const float*)d_in[13];

  float* out   = (float*)d_out;           // log_softmax output (logits in place first)
  float* hnew  = out + (size_t)B_ * KY;   // h_new

  int gis = 5, ghs = 2;
  size_t need = (size_t)(65536 + 131072 + 8192 + 131072 + 163840
                         + gis * 196608 + ghs * 196608 + 98304 + 64) * 4;
  if (ws_size < need) { gis = 1; ghs = 1; }

  float* ws = (float*)d_ws;
  float* hpart     = ws;                         // 64*1024
  float* scorepart = hpart + 65536;              // 16*8192
  float* w         = scorepart + 131072;         // 8192
  float* context   = w + 8192;                   // 64*2048
  float* rnn_in    = context + 131072;           // 64*2560
  float* gi        = rnn_in + 163840;            // gis*64*3072
  float* gh        = gi + (size_t)gis * 196608;  // ghs*64*3072
  unsigned short* xb = (unsigned short*)(gh + (size_t)ghs * 196608); // 64*3072 bf16
  float* lse       = (float*)(xb + 196608);      // 64

  k1_hpart<<<dim3(256, 64), 256, 0, stream>>>(hidden, aW1, ab1, hpart);
  k2_gemm_score<<<dim3(M_ / 64, 16), 256, 0, stream>>>(enc, aW1, hpart, aW2, scorepart);
  k3_softmax<<<B_, TX, 0, stream>>>(scorepart, ab2, w);
  k4_context<<<dim3(H2 / 256, B_), 256, 0, stream>>>(enc, w, context);
  k5a_rnnin<<<B_, 256, 0, stream>>>(input, emb_W, context, rnn_in);
  k_gemm_T<<<dim3(H3 / 64, gis), 256, 0, stream>>>(rnn_in, Wih, bih, gi, H3, EC);
  k_gemm_T<<<dim3(H3 / 64, ghs), 256, 0, stream>>>(hidden, Whh, bhh, gh, H3, H_);
  k5c_gates<<<B_, 256, 0, stream>>>(gi, gh, gis, ghs, hidden, context, hnew, xb);
  k6_lsm_mfma<<<KY / 64, 256, 0, stream>>>(xb, lsm_W, lsm_b, out);
  k7_lse<<<B_, 256, 0, stream>>>(out, lse);
  k8_out<<<dim3(KY / 256, B_), 256, 0, stream>>>(out, lse);
}

// Round 5
// 502.897 us; speedup vs baseline: 3.4898x; 1.7885x over previous
//
#include <hip/hip_runtime.h>
#include <hip/hip_bf16.h>

#define B_  64
#define TX  128
#define H_  1024
#define E_  512
#define KY  32000
#define H2  2048   // 2H
#define H3  3072   // 3H
#define EC  2560   // E+2H
#define M_  (TX*B_) // 8192
#define WST 132    // LDS row stride for f32 W tile (k_gemm_T)
#define SP  72     // LDS k-stride (bf16 elems) for k2_mfma tiles

typedef __bf16 bf16x8 __attribute__((ext_vector_type(8)));
typedef unsigned short u16x8 __attribute__((ext_vector_type(8)));
typedef float f32x4 __attribute__((ext_vector_type(4)));

// f32 -> bf16 round-to-nearest-even
__device__ __forceinline__ unsigned short f2bf(float f) {
  unsigned int u = __builtin_bit_cast(unsigned int, f);
  u += 0x7fff + ((u >> 16) & 1);
  return (unsigned short)(u >> 16);
}
__device__ __forceinline__ float bf2f(unsigned short s) {
  return __builtin_bit_cast(float, (unsigned int)s << 16);
}

// ---------------- converts: f32 -> bf16 ----------------
__global__ void kc_enc2bf(const float* __restrict__ src, unsigned short* __restrict__ dst) {
  size_t i = ((size_t)blockIdx.x * 256 + threadIdx.x) * 8;
  float4 v0 = *(const float4*)(src + i);
  float4 v1 = *(const float4*)(src + i + 4);
  u16x8 o;
  o[0]=f2bf(v0.x); o[1]=f2bf(v0.y); o[2]=f2bf(v0.z); o[3]=f2bf(v0.w);
  o[4]=f2bf(v1.x); o[5]=f2bf(v1.y); o[6]=f2bf(v1.z); o[7]=f2bf(v1.w);
  *(u16x8*)(dst + i) = o;
}
// w1_b[n][k] = bf16(aW1[n][H_+k]), n<1024, k<2048
__global__ void kc_w12bf(const float* __restrict__ aW1, unsigned short* __restrict__ dst) {
  size_t idx = ((size_t)blockIdx.x * 256 + threadIdx.x) * 8;
  int row = (int)(idx >> 11);
  int col = (int)(idx & 2047);
  const float* s = aW1 + (size_t)row * H3 + H_ + col;
  float4 v0 = *(const float4*)(s);
  float4 v1 = *(const float4*)(s + 4);
  u16x8 o;
  o[0]=f2bf(v0.x); o[1]=f2bf(v0.y); o[2]=f2bf(v0.z); o[3]=f2bf(v0.w);
  o[4]=f2bf(v1.x); o[5]=f2bf(v1.y); o[6]=f2bf(v1.z); o[7]=f2bf(v1.w);
  *(u16x8*)(dst + idx) = o;
}

// ---------------- K1: hpart[b][h] = ab1[h] + hidden[b,:] . aW1[h, :H] ----------------
__global__ void k1_hpart(const float* __restrict__ hidden, const float* __restrict__ aW1,
                         const float* __restrict__ ab1, float* __restrict__ hpart) {
  int b = blockIdx.y;
  int wave = threadIdx.x >> 6;
  int lane = threadIdx.x & 63;
  int h = blockIdx.x * 4 + wave;
  const float* wrow = aW1 + (size_t)h * H3;
  const float* hrow = hidden + b * H_;
  float acc = 0.f;
  for (int j = 0; j < H_ / 64; ++j) {
    int i = j * 64 + lane;
    acc += hrow[i] * wrow[i];
  }
  for (int off = 32; off; off >>= 1) acc += __shfl_down(acc, off);
  if (lane == 0) hpart[b * H_ + h] = acc + ab1[h];
}

// ---------------- K2 (MFMA): 8192x1024 over K=2048, bf16, fused tanh+aW2 reduce ----------------
// scorepart[nt][m] = sum over this n-tile's 128 n of aW2[n]*tanh(hpart[b][n] + C[m][n])
__global__ __launch_bounds__(256) void k2_mfma(
    const unsigned short* __restrict__ encb, const unsigned short* __restrict__ w1b,
    const float* __restrict__ hpart, const float* __restrict__ aW2,
    float* __restrict__ scorepart) {
  __shared__ __align__(16) unsigned short As[128 * SP];
  __shared__ __align__(16) unsigned short Bs[128 * SP];
  __shared__ float red[128][2];
  int wg = blockIdx.x;                      // 512 blocks
  int swz = (wg & 7) * 64 + (wg >> 3);      // bijective XCD swizzle (512 = 8*64)
  int mt = swz >> 3, nt = swz & 7;
  int m0 = mt * 128, n0 = nt * 128;
  int tid = threadIdx.x;
  int lane = tid & 63, wid = tid >> 6;
  int wr = wid >> 1, wc = wid & 1;          // 2x2 wave grid, 64x64 out per wave
  f32x4 z = {0.f, 0.f, 0.f, 0.f};
  f32x4 acc[4][4];
  #pragma unroll
  for (int i = 0; i < 4; ++i)
    #pragma unroll
    for (int j = 0; j < 4; ++j) acc[i][j] = z;

  int srow = tid >> 3, sch = tid & 7;       // staging: 8 chunks of 8 bf16 per 64-col row
  for (int k0 = 0; k0 < H2; k0 += 64) {
    __syncthreads();
    #pragma unroll
    for (int i = 0; i < 4; ++i) {
      int row = srow + i * 32;
      u16x8 av = *(const u16x8*)&encb[(size_t)(m0 + row) * H2 + k0 + sch * 8];
      u16x8 bv = *(const u16x8*)&w1b[(size_t)(n0 + row) * H2 + k0 + sch * 8];
      *(u16x8*)&As[row * SP + sch * 8] = av;
      *(u16x8*)&Bs[row * SP + sch * 8] = bv;
    }
    __syncthreads();
    #pragma unroll
    for (int ks = 0; ks < 2; ++ks) {
      bf16x8 af[4], bfr[4];
      #pragma unroll
      for (int i = 0; i < 4; ++i) {
        af[i]  = *(const bf16x8*)&As[(wr * 64 + i * 16 + (lane & 15)) * SP + ks * 32 + (lane >> 4) * 8];
        bfr[i] = *(const bf16x8*)&Bs[(wc * 64 + i * 16 + (lane & 15)) * SP + ks * 32 + (lane >> 4) * 8];
      }
      #pragma unroll
      for (int mi = 0; mi < 4; ++mi)
        #pragma unroll
        for (int ni = 0; ni < 4; ++ni)
          acc[mi][ni] = __builtin_amdgcn_mfma_f32_16x16x32_bf16(af[mi], bfr[ni], acc[mi][ni], 0, 0, 0);
    }
  }
  // epilogue: p[m] = sum_n aW2[n]*tanh(hpart[b][n] + C[m][n]) over this wave's 64 n
  int q = lane >> 4, c = lane & 15;
  #pragma unroll
  for (int mi = 0; mi < 4; ++mi) {
    #pragma unroll
    for (int r = 0; r < 4; ++r) {
      int mloc = wr * 64 + mi * 16 + q * 4 + r;
      int b = (mi * 16 + q * 4 + r) & 63;   // (m0+mloc)&63, m0%64==0, wr*64%64==0
      float p = 0.f;
      #pragma unroll
      for (int ni = 0; ni < 4; ++ni) {
        int n = n0 + wc * 64 + ni * 16 + c;
        p += aW2[n] * tanhf(hpart[b * H_ + n] + acc[mi][ni][r]);
      }
      p += __shfl_xor(p, 1); p += __shfl_xor(p, 2);
      p += __shfl_xor(p, 4); p += __shfl_xor(p, 8);
      if (c == 0) red[mloc][wc] = p;
    }
  }
  __syncthreads();
  if (tid < 128)
    scorepart[(size_t)nt * M_ + m0 + tid] = red[tid][0] + red[tid][1];
}

// ---------------- K2 fallback (f32 vector), writes scorepart with 16 n-blocks ----------------
__global__ __launch_bounds__(256) void k2_gemm_score(
    const float* __restrict__ enc, const float* __restrict__ aW1,
    const float* __restrict__ hpart, const float* __restrict__ aW2,
    float* __restrict__ scorepart) {
  __shared__ float As[32][68];
  __shared__ float Bs[32][68];
  __shared__ float red[64][17];
  int m0 = blockIdx.x * 64;
  int n0 = blockIdx.y * 64;
  int tid = threadIdx.x;
  int ty = tid >> 4, tx = tid & 15;
  float acc[4][4] = {};
  for (int k0 = 0; k0 < H2; k0 += 32) {
    #pragma unroll
    for (int l = 0; l < 2; ++l) {
      int fi = tid + l * 256;
      int m = fi >> 3;
      int kq = (fi & 7) * 4;
      const float4 v = *(const float4*)&enc[(size_t)(m0 + m) * H2 + k0 + kq];
      As[kq + 0][m] = v.x; As[kq + 1][m] = v.y; As[kq + 2][m] = v.z; As[kq + 3][m] = v.w;
      const float4 u = *(const float4*)&aW1[(size_t)(n0 + m) * H3 + H_ + k0 + kq];
      Bs[kq + 0][m] = u.x; Bs[kq + 1][m] = u.y; Bs[kq + 2][m] = u.z; Bs[kq + 3][m] = u.w;
    }
    __syncthreads();
    #pragma unroll
    for (int kk = 0; kk < 32; ++kk) {
      float4 av = *(const float4*)&As[kk][ty * 4];
      float4 bv = *(const float4*)&Bs[kk][tx * 4];
      float a[4] = {av.x, av.y, av.z, av.w};
      float b[4] = {bv.x, bv.y, bv.z, bv.w};
      #pragma unroll
      for (int i = 0; i < 4; ++i)
        #pragma unroll
        for (int j = 0; j < 4; ++j)
          acc[i][j] += a[i] * b[j];
    }
    __syncthreads();
  }
  #pragma unroll
  for (int i = 0; i < 4; ++i) {
    int m = m0 + ty * 4 + i;
    int bb = m & 63;
    float p = 0.f;
    #pragma unroll
    for (int j = 0; j < 4; ++j) {
      int n = n0 + tx * 4 + j;
      p += aW2[n] * tanhf(hpart[bb * H_ + n] + acc[i][j]);
    }
    red[ty * 4 + i][tx] = p;
  }
  __syncthreads();
  if (tid < 64) {
    float s = 0.f;
    #pragma unroll
    for (int j = 0; j < 16; ++j) s += red[tid][j];
    scorepart[(size_t)blockIdx.y * M_ + m0 + tid] = s;
  }
}

// ---------------- K3: softmax over t (per b); nb = number of scorepart blocks ----------------
__global__ void k3_softmax(const float* __restrict__ scorepart, const float* __restrict__ ab2,
                           float* __restrict__ w, int nb) {
  int b = blockIdx.x;
  int t = threadIdx.x; // 128
  float s = ab2[0];
  for (int k = 0; k < nb; ++k) s += scorepart[k * M_ + t * B_ + b];
  __shared__ float sm[128];
  sm[t] = s; __syncthreads();
  for (int off = 64; off; off >>= 1) {
    if (t < off) sm[t] = fmaxf(sm[t], sm[t + off]);
    __syncthreads();
  }
  float mx = sm[0]; __syncthreads();
  float e = expf(s - mx);
  sm[t] = e; __syncthreads();
  for (int off = 64; off; off >>= 1) {
    if (t < off) sm[t] += sm[t + off];
    __syncthreads();
  }
  w[t * B_ + b] = e / sm[0];
}

// ---------------- K4 (bf16 enc): context[b][k] = sum_t w[t][b]*enc[t][b][k] ----------------
__global__ void k4_context_bf(const unsigned short* __restrict__ encb, const float* __restrict__ w,
                              float* __restrict__ context) {
  int b = blockIdx.y;
  int kp = blockIdx.x * 256 + threadIdx.x;  // pair index, 1024 per row
  __shared__ float wl[TX];
  if (threadIdx.x < TX) wl[threadIdx.x] = w[threadIdx.x * B_ + b];
  __syncthreads();
  float a0 = 0.f, a1 = 0.f;
  for (int t = 0; t < TX; ++t) {
    unsigned int u = *(const unsigned int*)&encb[((size_t)t * B_ + b) * H2 + kp * 2];
    float e0 = __builtin_bit_cast(float, u << 16);
    float e1 = __builtin_bit_cast(float, u & 0xffff0000u);
    float wt = wl[t];
    a0 += wt * e0; a1 += wt * e1;
  }
  float2 o; o.x = a0; o.y = a1;
  *(float2*)&context[b * H2 + kp * 2] = o;
}
// f32 fallback
__global__ void k4_context(const float* __restrict__ enc, const float* __restrict__ w,
                           float* __restrict__ context) {
  int b = blockIdx.y;
  int k = blockIdx.x * 256 + threadIdx.x;
  __shared__ float wl[TX];
  if (threadIdx.x < TX) wl[threadIdx.x] = w[threadIdx.x * B_ + b];
  __syncthreads();
  float acc = 0.f;
  for (int t = 0; t < TX; ++t)
    acc += wl[t] * enc[((size_t)t * B_ + b) * H2 + k];
  context[b * H2 + k] = acc;
}

// ---------------- K5a: rnn_in = [embed, context] ----------------
__global__ void k5a_rnnin(const int* __restrict__ input, const float* __restrict__ emb_W,
                          const float* __restrict__ context, float* __restrict__ rnn_in) {
  int b = blockIdx.x;
  int tok = input[b];
  for (int c = threadIdx.x; c < EC; c += blockDim.x)
    rnn_in[b * EC + c] = (c < E_) ? emb_W[(size_t)tok * E_ + c] : context[b * H2 + (c - E_)];
}

// ---------------- small-M GEMM (gi/gh): W tile staged in LDS, x in regs ----------------
__global__ __launch_bounds__(256) void k_gemm_T(
    const float* __restrict__ x, const float* __restrict__ W,
    const float* __restrict__ bias, float* __restrict__ out, int N, int K) {
  __shared__ float Ws[64 * WST];
  int tid = threadIdx.x;
  int b = tid & 63, g = tid >> 6;
  int n0 = blockIdx.x * 64;
  int ks = blockIdx.y;
  int kchunk = K / gridDim.y;
  int kbeg = ks * kchunk, kend = kbeg + kchunk;
  float acc[16] = {};
  const float4* xv = (const float4*)(x + (size_t)b * K);
  for (int k0 = kbeg; k0 < kend; k0 += 128) {
    __syncthreads();
    #pragma unroll
    for (int l = 0; l < 8; ++l) {
      int f = l * 256 + tid;
      int row = f >> 5, c4 = f & 31;
      float4 v = *(const float4*)&W[(size_t)(n0 + row) * K + k0 + c4 * 4];
      *(float4*)&Ws[row * WST + c4 * 4] = v;
    }
    __syncthreads();
    #pragma unroll
    for (int kb = 0; kb < 128; kb += 16) {
      float4 x0 = xv[(k0 + kb) / 4 + 0];
      float4 x1 = xv[(k0 + kb) / 4 + 1];
      float4 x2 = xv[(k0 + kb) / 4 + 2];
      float4 x3 = xv[(k0 + kb) / 4 + 3];
      #pragma unroll
      for (int i = 0; i < 16; ++i) {
        const float* wr = &Ws[(g * 16 + i) * WST + kb];
        float4 w0 = *(const float4*)(wr + 0);
        float4 w1 = *(const float4*)(wr + 4);
        float4 w2 = *(const float4*)(wr + 8);
        float4 w3 = *(const float4*)(wr + 12);
        acc[i] += x0.x*w0.x + x0.y*w0.y + x0.z*w0.z + x0.w*w0.w
                + x1.x*w1.x + x1.y*w1.y + x1.z*w1.z + x1.w*w1.w
                + x2.x*w2.x + x2.y*w2.y + x2.z*w2.z + x2.w*w2.w
                + x3.x*w3.x + x3.y*w3.y + x3.z*w3.z + x3.w*w3.w;
      }
    }
  }
  float* po = out + (size_t)ks * 64 * N;
  #pragma unroll
  for (int i = 0; i < 16; ++i) {
    int n = n0 + g * 16 + i;
    float v = acc[i];
    if (ks == 0) v += bias[n];
    po[(size_t)b * N + n] = v;
  }
}

// ---------------- K5c: k-split partials -> GRU gates; writes hnew + xb (bf16 [h_new,context]) ----------------
__global__ void k5c_gates(const float* __restrict__ gip, const float* __restrict__ ghp,
                          int gis, int ghs,
                          const float* __restrict__ hidden, const float* __restrict__ context,
                          float* __restrict__ hnew_out, unsigned short* __restrict__ xb) {
  int b = blockIdx.x;
  for (int h = threadIdx.x; h < H_; h += blockDim.x) {
    float ir = 0.f, iz = 0.f, inn = 0.f;
    for (int s = 0; s < gis; ++s) {
      const float* gb = gip + (size_t)s * B_ * H3 + (size_t)b * H3;
      ir += gb[h]; iz += gb[H_ + h]; inn += gb[H2 + h];
    }
    float hr = 0.f, hz = 0.f, hn = 0.f;
    for (int s = 0; s < ghs; ++s) {
      const float* gb = ghp + (size_t)s * B_ * H3 + (size_t)b * H3;
      hr += gb[h]; hz += gb[H_ + h]; hn += gb[H2 + h];
    }
    float r = 1.f / (1.f + expf(-(ir + hr)));
    float z = 1.f / (1.f + expf(-(iz + hz)));
    float n = tanhf(inn + r * hn);
    float hv = hidden[b * H_ + h];
    float hnew = (1.f - z) * n + z * hv;
    hnew_out[b * H_ + h] = hnew;
    xb[b * H3 + h] = f2bf(hnew);
  }
  for (int c = threadIdx.x; c < H2; c += blockDim.x)
    xb[b * H3 + H_ + c] = f2bf(context[b * H2 + c]);
}

// ---------------- K6: lsm logits via bf16 MFMA, W converted on the fly ----------------
__global__ __launch_bounds__(256) void k6_lsm_mfma(
    const unsigned short* __restrict__ xb, const float* __restrict__ W,
    const float* __restrict__ bias, float* __restrict__ out) {
  int tid = threadIdx.x;
  int wv = tid >> 6, lane = tid & 63;
  int n = blockIdx.x * 64 + wv * 16 + (lane & 15);
  int kg = lane >> 4;
  const float* wp = W + (size_t)n * H3 + kg * 8;
  const unsigned short* xp = xb + (size_t)(lane & 15) * H3 + kg * 8;
  f32x4 a0 = {0.f, 0.f, 0.f, 0.f}, a1 = a0, a2 = a0, a3 = a0;
  #pragma unroll 2
  for (int k0 = 0; k0 < H3; k0 += 32) {
    float4 wlo = *(const float4*)(wp + k0);
    float4 whi = *(const float4*)(wp + k0 + 4);
    u16x8 bu;
    bu[0] = f2bf(wlo.x); bu[1] = f2bf(wlo.y); bu[2] = f2bf(wlo.z); bu[3] = f2bf(wlo.w);
    bu[4] = f2bf(whi.x); bu[5] = f2bf(whi.y); bu[6] = f2bf(whi.z); bu[7] = f2bf(whi.w);
    bf16x8 bf = __builtin_bit_cast(bf16x8, bu);
    u16x8 x0 = *(const u16x8*)(xp + k0);
    u16x8 x1 = *(const u16x8*)(xp + 16 * H3 + k0);
    u16x8 x2 = *(const u16x8*)(xp + 32 * H3 + k0);
    u16x8 x3 = *(const u16x8*)(xp + 48 * H3 + k0);
    a0 = __builtin_amdgcn_mfma_f32_16x16x32_bf16(__builtin_bit_cast(bf16x8, x0), bf, a0, 0, 0, 0);
    a1 = __builtin_amdgcn_mfma_f32_16x16x32_bf16(__builtin_bit_cast(bf16x8, x1), bf, a1, 0, 0, 0);
    a2 = __builtin_amdgcn_mfma_f32_16x16x32_bf16(__builtin_bit_cast(bf16x8, x2), bf, a2, 0, 0, 0);
    a3 = __builtin_amdgcn_mfma_f32_16x16x32_bf16(__builtin_bit_cast(bf16x8, x3), bf, a3, 0, 0, 0);
  }
  float bv = bias[n];
  int r0 = kg * 4;
  #pragma unroll
  for (int r = 0; r < 4; ++r) {
    out[(size_t)(r0 + r) * KY + n]      = a0[r] + bv;
    out[(size_t)(16 + r0 + r) * KY + n] = a1[r] + bv;
    out[(size_t)(32 + r0 + r) * KY + n] = a2[r] + bv;
    out[(size_t)(48 + r0 + r) * KY + n] = a3[r] + bv;
  }
}

// ---------------- K7: per-row logsumexp of logits ----------------
__global__ void k7_lse(const float* __restrict__ logits, float* __restrict__ lse) {
  int b = blockIdx.x;
  const float* row = logits + (size_t)b * KY;
  __shared__ float sm[256];
  float mx = -1e30f;
  for (int k = threadIdx.x; k < KY; k += 256) mx = fmaxf(mx, row[k]);
  sm[threadIdx.x] = mx; __syncthreads();
  for (int off = 128; off; off >>= 1) {
    if (threadIdx.x < off) sm[threadIdx.x] = fmaxf(sm[threadIdx.x], sm[threadIdx.x + off]);
    __syncthreads();
  }
  mx = sm[0]; __syncthreads();
  float s = 0.f;
  for (int k = threadIdx.x; k < KY; k += 256) s += expf(row[k] - mx);
  sm[threadIdx.x] = s; __syncthreads();
  for (int off = 128; off; off >>= 1) {
    if (threadIdx.x < off) sm[threadIdx.x] += sm[threadIdx.x + off];
    __syncthreads();
  }
  if (threadIdx.x == 0) lse[b] = mx + logf(sm[0]);
}

// ---------------- K8: in-place out = logits - lse ----------------
__global__ void k8_out(float* __restrict__ outp, const float* __restrict__ lse) {
  int b = blockIdx.y;
  int k = blockIdx.x * 256 + threadIdx.x;
  size_t idx = (size_t)b * KY + k;
  outp[idx] = outp[idx] - lse[b];
}

extern "C" void kernel_launch(void* const* d_in, const int* in_sizes, int n_in,
                              void* d_out, int out_size, void* d_ws, size_t ws_size,
                              hipStream_t stream) {
  const int*   input  = (const int*)  d_in[0];
  const float* hidden = (const float*)d_in[1];
  const float* enc    = (const float*)d_in[2];
  const float* emb_W  = (const float*)d_in[3];
  const float* Wih    = (const float*)d_in[4];
  const float* Whh    = (const float*)d_in[5];
  const float* bih    = (const float*)d_in[6];
  const float* bhh    = (const float*)d_in[7];
  const float* lsm_W  = (const float*)d_in[8];
  const float* lsm_b  = (const float*)d_in[9];
  const float* aW1    = (const float*)d_in[10];
  const float* ab1    = (const float*)d_in[11];
  const float* aW2    = (const float*)d_in[12];
  const float* ab2    = (const float*)d_in[13];

  float* out   = (float*)d_out;           // log_softmax output (logits in place first)
  float* hnew  = out + (size_t)B_ * KY;   // h_new

  int gis = 5, ghs = 2;
  // fast path needs: encb 8388608 + w1b 1048576 floats of bf16 storage + f32 scratch
  size_t base_f = 65536 + 131072 + 8192 + 131072 + 163840
                + (size_t)gis * 196608 + (size_t)ghs * 196608 + 98304 + 64;
  size_t need_fast = (base_f + 8388608 + 1048576) * 4;
  int fast = (ws_size >= need_fast);
  if (!fast) {
    size_t need_slow = base_f * 4;
    if (ws_size < need_slow) { gis = 1; ghs = 1; }
  }

  float* ws = (float*)d_ws;
  unsigned short* encb = (unsigned short*)ws;                    // 16.8M bf16 (fast only)
  unsigned short* w1b  = encb + (fast ? 16777216 : 0);           // 2.1M bf16 (fast only)
  float* fbase = fast ? (float*)(w1b + 2097152) : ws;
  float* hpart     = fbase;                          // 64*1024
  float* scorepart = hpart + 65536;                  // up to 16*8192
  float* w         = scorepart + 131072;             // 8192
  float* context   = w + 8192;                       // 64*2048
  float* rnn_in    = context + 131072;               // 64*2560
  float* gi        = rnn_in + 163840;                // gis*64*3072
  float* gh        = gi + (size_t)gis * 196608;      // ghs*64*3072
  unsigned short* xb = (unsigned short*)(gh + (size_t)ghs * 196608); // 64*3072 bf16
  float* lse       = (float*)(xb + 196608);          // 64

  k1_hpart<<<dim3(256, 64), 256, 0, stream>>>(hidden, aW1, ab1, hpart);
  if (fast) {
    kc_enc2bf<<<8192, 256, 0, stream>>>(enc, encb);
    kc_w12bf<<<1024, 256, 0, stream>>>(aW1, w1b);
    k2_mfma<<<512, 256, 0, stream>>>(encb, w1b, hpart, aW2, scorepart);
    k3_softmax<<<B_, TX, 0, stream>>>(scorepart, ab2, w, 8);
    k4_context_bf<<<dim3(4, B_), 256, 0, stream>>>(encb, w, context);
  } else {
    k2_gemm_score<<<dim3(M_ / 64, 16), 256, 0, stream>>>(enc, aW1, hpart, aW2, scorepart);
    k3_softmax<<<B_, TX, 0, stream>>>(scorepart, ab2, w, 16);
    k4_context<<<dim3(H2 / 256, B_), 256, 0, stream>>>(enc, w, context);
  }
  k5a_rnnin<<<B_, 256, 0, stream>>>(input, emb_W, context, rnn_in);
  k_gemm_T<<<dim3(H3 / 64, gis), 256, 0, stream>>>(rnn_in, Wih, bih, gi, H3, EC);
  k_gemm_T<<<dim3(H3 / 64, ghs), 256, 0, stream>>>(hidden, Whh, bhh, gh, H3, H_);
  k5c_gates<<<B_, 256, 0, stream>>>(gi, gh, gis, ghs, hidden, context, hnew, xb);
  k6_lsm_mfma<<<KY / 64, 256, 0, stream>>>(xb, lsm_W, lsm_b, out);
  k7_lse<<<B_, 256, 0, stream>>>(out, lse);
  k8_out<<<dim3(KY / 256, B_), 256, 0, stream>>>(out, lse);
}

// Round 6
// 443.774 us; speedup vs baseline: 3.9547x; 1.1332x over previous
//
#include <hip/hip_runtime.h>
#include <hip/hip_bf16.h>

#define B_  64
#define TX  128
#define H_  1024
#define E_  512
#define KY  32000
#define H2  2048   // 2H
#define H3  3072   // 3H
#define EC  2560   // E+2H
#define M_  (TX*B_) // 8192
#define WST 132    // LDS row stride for f32 W tile (gemmT)
#define SP  72     // LDS k-stride (bf16 elems) for k2_mfma tiles

typedef __bf16 bf16x8 __attribute__((ext_vector_type(8)));
typedef unsigned short u16x8 __attribute__((ext_vector_type(8)));
typedef float f32x4 __attribute__((ext_vector_type(4)));

// f32 -> bf16 round-to-nearest-even
__device__ __forceinline__ unsigned short f2bf(float f) {
  unsigned int u = __builtin_bit_cast(unsigned int, f);
  u += 0x7fff + ((u >> 16) & 1);
  return (unsigned short)(u >> 16);
}

// ---------------- merged convert: enc -> encb  and  aW1[:,H:] -> w1b ----------------
__global__ void kc_all(const float* __restrict__ enc, const float* __restrict__ aW1,
                       unsigned short* __restrict__ encb, unsigned short* __restrict__ w1b) {
  size_t gid = (size_t)blockIdx.x * 256 + threadIdx.x;
  if (gid < 2097152) {            // enc: 16777216 elems = 2097152 threads x 8
    size_t i = gid * 8;
    float4 v0 = *(const float4*)(enc + i);
    float4 v1 = *(const float4*)(enc + i + 4);
    u16x8 o;
    o[0]=f2bf(v0.x); o[1]=f2bf(v0.y); o[2]=f2bf(v0.z); o[3]=f2bf(v0.w);
    o[4]=f2bf(v1.x); o[5]=f2bf(v1.y); o[6]=f2bf(v1.z); o[7]=f2bf(v1.w);
    *(u16x8*)(encb + i) = o;
  } else {                        // w1: 2097152 elems = 262144 threads x 8
    size_t idx = (gid - 2097152) * 8;
    int row = (int)(idx >> 11);
    int col = (int)(idx & 2047);
    const float* s = aW1 + (size_t)row * H3 + H_ + col;
    float4 v0 = *(const float4*)(s);
    float4 v1 = *(const float4*)(s + 4);
    u16x8 o;
    o[0]=f2bf(v0.x); o[1]=f2bf(v0.y); o[2]=f2bf(v0.z); o[3]=f2bf(v0.w);
    o[4]=f2bf(v1.x); o[5]=f2bf(v1.y); o[6]=f2bf(v1.z); o[7]=f2bf(v1.w);
    *(u16x8*)(w1b + idx) = o;
  }
}

// ---------------- K1: hpart[b][h] = ab1[h] + hidden[b,:] . aW1[h, :H] ----------------
__global__ void k1_hpart(const float* __restrict__ hidden, const float* __restrict__ aW1,
                         const float* __restrict__ ab1, float* __restrict__ hpart) {
  int b = blockIdx.y;
  int wave = threadIdx.x >> 6;
  int lane = threadIdx.x & 63;
  int h = blockIdx.x * 4 + wave;
  const float* wrow = aW1 + (size_t)h * H3;
  const float* hrow = hidden + b * H_;
  float acc = 0.f;
  for (int j = 0; j < H_ / 64; ++j) {
    int i = j * 64 + lane;
    acc += hrow[i] * wrow[i];
  }
  for (int off = 32; off; off >>= 1) acc += __shfl_down(acc, off);
  if (lane == 0) hpart[b * H_ + h] = acc + ab1[h];
}

// ---------------- K2 (MFMA): 8192x1024 over K=2048, bf16, fused tanh+aW2 reduce ----------------
__global__ __launch_bounds__(256) void k2_mfma(
    const unsigned short* __restrict__ encb, const unsigned short* __restrict__ w1b,
    const float* __restrict__ hpart, const float* __restrict__ aW2,
    float* __restrict__ scorepart) {
  __shared__ __align__(16) unsigned short As[128 * SP];
  __shared__ __align__(16) unsigned short Bs[128 * SP];
  __shared__ float red[128][2];
  int wg = blockIdx.x;                      // 512 blocks
  int swz = (wg & 7) * 64 + (wg >> 3);      // bijective XCD swizzle (512 = 8*64)
  int mt = swz >> 3, nt = swz & 7;
  int m0 = mt * 128, n0 = nt * 128;
  int tid = threadIdx.x;
  int lane = tid & 63, wid = tid >> 6;
  int wr = wid >> 1, wc = wid & 1;          // 2x2 wave grid, 64x64 out per wave
  f32x4 z = {0.f, 0.f, 0.f, 0.f};
  f32x4 acc[4][4];
  #pragma unroll
  for (int i = 0; i < 4; ++i)
    #pragma unroll
    for (int j = 0; j < 4; ++j) acc[i][j] = z;

  int srow = tid >> 3, sch = tid & 7;
  for (int k0 = 0; k0 < H2; k0 += 64) {
    __syncthreads();
    #pragma unroll
    for (int i = 0; i < 4; ++i) {
      int row = srow + i * 32;
      u16x8 av = *(const u16x8*)&encb[(size_t)(m0 + row) * H2 + k0 + sch * 8];
      u16x8 bv = *(const u16x8*)&w1b[(size_t)(n0 + row) * H2 + k0 + sch * 8];
      *(u16x8*)&As[row * SP + sch * 8] = av;
      *(u16x8*)&Bs[row * SP + sch * 8] = bv;
    }
    __syncthreads();
    #pragma unroll
    for (int ks = 0; ks < 2; ++ks) {
      bf16x8 af[4], bfr[4];
      #pragma unroll
      for (int i = 0; i < 4; ++i) {
        af[i]  = *(const bf16x8*)&As[(wr * 64 + i * 16 + (lane & 15)) * SP + ks * 32 + (lane >> 4) * 8];
        bfr[i] = *(const bf16x8*)&Bs[(wc * 64 + i * 16 + (lane & 15)) * SP + ks * 32 + (lane >> 4) * 8];
      }
      #pragma unroll
      for (int mi = 0; mi < 4; ++mi)
        #pragma unroll
        for (int ni = 0; ni < 4; ++ni)
          acc[mi][ni] = __builtin_amdgcn_mfma_f32_16x16x32_bf16(af[mi], bfr[ni], acc[mi][ni], 0, 0, 0);
    }
  }
  int q = lane >> 4, c = lane & 15;
  #pragma unroll
  for (int mi = 0; mi < 4; ++mi) {
    #pragma unroll
    for (int r = 0; r < 4; ++r) {
      int mloc = wr * 64 + mi * 16 + q * 4 + r;
      int b = (mi * 16 + q * 4 + r) & 63;
      float p = 0.f;
      #pragma unroll
      for (int ni = 0; ni < 4; ++ni) {
        int n = n0 + wc * 64 + ni * 16 + c;
        p += aW2[n] * tanhf(hpart[b * H_ + n] + acc[mi][ni][r]);
      }
      p += __shfl_xor(p, 1); p += __shfl_xor(p, 2);
      p += __shfl_xor(p, 4); p += __shfl_xor(p, 8);
      if (c == 0) red[mloc][wc] = p;
    }
  }
  __syncthreads();
  if (tid < 128)
    scorepart[(size_t)nt * M_ + m0 + tid] = red[tid][0] + red[tid][1];
}

// ---------------- K2 fallback (f32 vector) ----------------
__global__ __launch_bounds__(256) void k2_gemm_score(
    const float* __restrict__ enc, const float* __restrict__ aW1,
    const float* __restrict__ hpart, const float* __restrict__ aW2,
    float* __restrict__ scorepart) {
  __shared__ float As[32][68];
  __shared__ float Bs[32][68];
  __shared__ float red[64][17];
  int m0 = blockIdx.x * 64;
  int n0 = blockIdx.y * 64;
  int tid = threadIdx.x;
  int ty = tid >> 4, tx = tid & 15;
  float acc[4][4] = {};
  for (int k0 = 0; k0 < H2; k0 += 32) {
    #pragma unroll
    for (int l = 0; l < 2; ++l) {
      int fi = tid + l * 256;
      int m = fi >> 3;
      int kq = (fi & 7) * 4;
      const float4 v = *(const float4*)&enc[(size_t)(m0 + m) * H2 + k0 + kq];
      As[kq + 0][m] = v.x; As[kq + 1][m] = v.y; As[kq + 2][m] = v.z; As[kq + 3][m] = v.w;
      const float4 u = *(const float4*)&aW1[(size_t)(n0 + m) * H3 + H_ + k0 + kq];
      Bs[kq + 0][m] = u.x; Bs[kq + 1][m] = u.y; Bs[kq + 2][m] = u.z; Bs[kq + 3][m] = u.w;
    }
    __syncthreads();
    #pragma unroll
    for (int kk = 0; kk < 32; ++kk) {
      float4 av = *(const float4*)&As[kk][ty * 4];
      float4 bv = *(const float4*)&Bs[kk][tx * 4];
      float a[4] = {av.x, av.y, av.z, av.w};
      float b[4] = {bv.x, bv.y, bv.z, bv.w};
      #pragma unroll
      for (int i = 0; i < 4; ++i)
        #pragma unroll
        for (int j = 0; j < 4; ++j)
          acc[i][j] += a[i] * b[j];
    }
    __syncthreads();
  }
  #pragma unroll
  for (int i = 0; i < 4; ++i) {
    int m = m0 + ty * 4 + i;
    int bb = m & 63;
    float p = 0.f;
    #pragma unroll
    for (int j = 0; j < 4; ++j) {
      int n = n0 + tx * 4 + j;
      p += aW2[n] * tanhf(hpart[bb * H_ + n] + acc[i][j]);
    }
    red[ty * 4 + i][tx] = p;
  }
  __syncthreads();
  if (tid < 64) {
    float s = 0.f;
    #pragma unroll
    for (int j = 0; j < 16; ++j) s += red[tid][j];
    scorepart[(size_t)blockIdx.y * M_ + m0 + tid] = s;
  }
}

// ---------------- K3: softmax over t (per b) ----------------
__global__ void k3_softmax(const float* __restrict__ scorepart, const float* __restrict__ ab2,
                           float* __restrict__ w, int nb) {
  int b = blockIdx.x;
  int t = threadIdx.x; // 128
  float s = ab2[0];
  for (int k = 0; k < nb; ++k) s += scorepart[k * M_ + t * B_ + b];
  __shared__ float sm[128];
  sm[t] = s; __syncthreads();
  for (int off = 64; off; off >>= 1) {
    if (t < off) sm[t] = fmaxf(sm[t], sm[t + off]);
    __syncthreads();
  }
  float mx = sm[0]; __syncthreads();
  float e = expf(s - mx);
  sm[t] = e; __syncthreads();
  for (int off = 64; off; off >>= 1) {
    if (t < off) sm[t] += sm[t + off];
    __syncthreads();
  }
  w[t * B_ + b] = e / sm[0];
}

// ---------------- K4 (bf16 enc) ----------------
__global__ void k4_context_bf(const unsigned short* __restrict__ encb, const float* __restrict__ w,
                              float* __restrict__ context) {
  int b = blockIdx.y;
  int kp = blockIdx.x * 256 + threadIdx.x;
  __shared__ float wl[TX];
  if (threadIdx.x < TX) wl[threadIdx.x] = w[threadIdx.x * B_ + b];
  __syncthreads();
  float a0 = 0.f, a1 = 0.f;
  for (int t = 0; t < TX; ++t) {
    unsigned int u = *(const unsigned int*)&encb[((size_t)t * B_ + b) * H2 + kp * 2];
    float e0 = __builtin_bit_cast(float, u << 16);
    float e1 = __builtin_bit_cast(float, u & 0xffff0000u);
    float wt = wl[t];
    a0 += wt * e0; a1 += wt * e1;
  }
  float2 o; o.x = a0; o.y = a1;
  *(float2*)&context[b * H2 + kp * 2] = o;
}
__global__ void k4_context(const float* __restrict__ enc, const float* __restrict__ w,
                           float* __restrict__ context) {
  int b = blockIdx.y;
  int k = blockIdx.x * 256 + threadIdx.x;
  __shared__ float wl[TX];
  if (threadIdx.x < TX) wl[threadIdx.x] = w[threadIdx.x * B_ + b];
  __syncthreads();
  float acc = 0.f;
  for (int t = 0; t < TX; ++t)
    acc += wl[t] * enc[((size_t)t * B_ + b) * H2 + k];
  context[b * H2 + k] = acc;
}

// ---------------- K5a: rnn_in = [embed, context] ----------------
__global__ void k5a_rnnin(const int* __restrict__ input, const float* __restrict__ emb_W,
                          const float* __restrict__ context, float* __restrict__ rnn_in) {
  int b = blockIdx.x;
  int tok = input[b];
  for (int c = threadIdx.x; c < EC; c += blockDim.x)
    rnn_in[b * EC + c] = (c < E_) ? emb_W[(size_t)tok * E_ + c] : context[b * H2 + (c - E_)];
}

// ---------------- shared gemmT body (small-M f32, W via LDS) ----------------
__device__ __forceinline__ void gemmT_body(const float* __restrict__ x,
    const float* __restrict__ W, const float* __restrict__ bias,
    float* __restrict__ po, int N, int K, int kbeg, int kend, bool addb,
    float* __restrict__ Ws) {
  int tid = threadIdx.x;
  int b = tid & 63, g = tid >> 6;
  int n0 = blockIdx.x * 64;
  float acc[16] = {};
  const float4* xv = (const float4*)(x + (size_t)b * K);
  for (int k0 = kbeg; k0 < kend; k0 += 128) {
    __syncthreads();
    #pragma unroll
    for (int l = 0; l < 8; ++l) {
      int f = l * 256 + tid;
      int row = f >> 5, c4 = f & 31;
      float4 v = *(const float4*)&W[(size_t)(n0 + row) * K + k0 + c4 * 4];
      *(float4*)&Ws[row * WST + c4 * 4] = v;
    }
    __syncthreads();
    #pragma unroll
    for (int kb = 0; kb < 128; kb += 16) {
      float4 x0 = xv[(k0 + kb) / 4 + 0];
      float4 x1 = xv[(k0 + kb) / 4 + 1];
      float4 x2 = xv[(k0 + kb) / 4 + 2];
      float4 x3 = xv[(k0 + kb) / 4 + 3];
      #pragma unroll
      for (int i = 0; i < 16; ++i) {
        const float* wr = &Ws[(g * 16 + i) * WST + kb];
        float4 w0 = *(const float4*)(wr + 0);
        float4 w1 = *(const float4*)(wr + 4);
        float4 w2 = *(const float4*)(wr + 8);
        float4 w3 = *(const float4*)(wr + 12);
        acc[i] += x0.x*w0.x + x0.y*w0.y + x0.z*w0.z + x0.w*w0.w
                + x1.x*w1.x + x1.y*w1.y + x1.z*w1.z + x1.w*w1.w
                + x2.x*w2.x + x2.y*w2.y + x2.z*w2.z + x2.w*w2.w
                + x3.x*w3.x + x3.y*w3.y + x3.z*w3.z + x3.w*w3.w;
      }
    }
  }
  #pragma unroll
  for (int i = 0; i < 16; ++i) {
    int n = n0 + g * 16 + i;
    float v = acc[i];
    if (addb) v += bias[n];
    po[(size_t)b * N + n] = v;
  }
}

// merged gi+gh: blockIdx.y 0..4 -> gi slice (K=2560), 5..6 -> gh slice (K=1024); kchunk=512
__global__ __launch_bounds__(256) void k_gates_gemm(
    const float* __restrict__ rnn_in, const float* __restrict__ Wih, const float* __restrict__ bih,
    const float* __restrict__ hidden, const float* __restrict__ Whh, const float* __restrict__ bhh,
    float* __restrict__ gi, float* __restrict__ gh) {
  __shared__ float Ws[64 * WST];
  int s = blockIdx.y;
  if (s < 5)
    gemmT_body(rnn_in, Wih, bih, gi + (size_t)s * B_ * H3, H3, EC, s * 512, s * 512 + 512, s == 0, Ws);
  else {
    int t = s - 5;
    gemmT_body(hidden, Whh, bhh, gh + (size_t)t * B_ * H3, H3, H_, t * 512, t * 512 + 512, t == 0, Ws);
  }
}

// legacy standalone (slow path)
__global__ __launch_bounds__(256) void k_gemm_T(
    const float* __restrict__ x, const float* __restrict__ W,
    const float* __restrict__ bias, float* __restrict__ out, int N, int K) {
  __shared__ float Ws[64 * WST];
  int ks = blockIdx.y;
  int kchunk = K / gridDim.y;
  gemmT_body(x, W, bias, out + (size_t)ks * 64 * N, N, K, ks * kchunk, ks * kchunk + kchunk, ks == 0, Ws);
}

// ---------------- K5c: GRU gates; writes hnew + xb ----------------
__global__ void k5c_gates(const float* __restrict__ gip, const float* __restrict__ ghp,
                          int gis, int ghs,
                          const float* __restrict__ hidden, const float* __restrict__ context,
                          float* __restrict__ hnew_out, unsigned short* __restrict__ xb) {
  int b = blockIdx.x;
  for (int h = threadIdx.x; h < H_; h += blockDim.x) {
    float ir = 0.f, iz = 0.f, inn = 0.f;
    for (int s = 0; s < gis; ++s) {
      const float* gb = gip + (size_t)s * B_ * H3 + (size_t)b * H3;
      ir += gb[h]; iz += gb[H_ + h]; inn += gb[H2 + h];
    }
    float hr = 0.f, hz = 0.f, hn = 0.f;
    for (int s = 0; s < ghs; ++s) {
      const float* gb = ghp + (size_t)s * B_ * H3 + (size_t)b * H3;
      hr += gb[h]; hz += gb[H_ + h]; hn += gb[H2 + h];
    }
    float r = 1.f / (1.f + expf(-(ir + hr)));
    float z = 1.f / (1.f + expf(-(iz + hz)));
    float n = tanhf(inn + r * hn);
    float hv = hidden[b * H_ + h];
    float hnew = (1.f - z) * n + z * hv;
    hnew_out[b * H_ + h] = hnew;
    xb[b * H3 + h] = f2bf(hnew);
  }
  for (int c = threadIdx.x; c < H2; c += blockDim.x)
    xb[b * H3 + H_ + c] = f2bf(context[b * H2 + c]);
}

// ---------------- K6 (fast): K-split x2 bf16 MFMA -> partials (no bias) ----------------
__global__ __launch_bounds__(256) void k6_split(
    const unsigned short* __restrict__ xb, const float* __restrict__ W,
    float* __restrict__ part) {
  int tid = threadIdx.x;
  int wv = tid >> 6, lane = tid & 63;
  int n = blockIdx.x * 64 + wv * 16 + (lane & 15);
  int kg = lane >> 4;
  int ks = blockIdx.y;                      // 2 halves of K=3072
  const float* wp = W + (size_t)n * H3 + ks * 1536 + kg * 8;
  const unsigned short* xp = xb + (size_t)(lane & 15) * H3 + ks * 1536 + kg * 8;
  f32x4 a0 = {0.f, 0.f, 0.f, 0.f}, a1 = a0, a2 = a0, a3 = a0;
  #pragma unroll 2
  for (int k0 = 0; k0 < 1536; k0 += 32) {
    float4 wlo = *(const float4*)(wp + k0);
    float4 whi = *(const float4*)(wp + k0 + 4);
    u16x8 bu;
    bu[0] = f2bf(wlo.x); bu[1] = f2bf(wlo.y); bu[2] = f2bf(wlo.z); bu[3] = f2bf(wlo.w);
    bu[4] = f2bf(whi.x); bu[5] = f2bf(whi.y); bu[6] = f2bf(whi.z); bu[7] = f2bf(whi.w);
    bf16x8 bf = __builtin_bit_cast(bf16x8, bu);
    u16x8 x0 = *(const u16x8*)(xp + k0);
    u16x8 x1 = *(const u16x8*)(xp + 16 * H3 + k0);
    u16x8 x2 = *(const u16x8*)(xp + 32 * H3 + k0);
    u16x8 x3 = *(const u16x8*)(xp + 48 * H3 + k0);
    a0 = __builtin_amdgcn_mfma_f32_16x16x32_bf16(__builtin_bit_cast(bf16x8, x0), bf, a0, 0, 0, 0);
    a1 = __builtin_amdgcn_mfma_f32_16x16x32_bf16(__builtin_bit_cast(bf16x8, x1), bf, a1, 0, 0, 0);
    a2 = __builtin_amdgcn_mfma_f32_16x16x32_bf16(__builtin_bit_cast(bf16x8, x2), bf, a2, 0, 0, 0);
    a3 = __builtin_amdgcn_mfma_f32_16x16x32_bf16(__builtin_bit_cast(bf16x8, x3), bf, a3, 0, 0, 0);
  }
  float* po = part + (size_t)ks * B_ * KY;
  int r0 = kg * 4;
  #pragma unroll
  for (int r = 0; r < 4; ++r) {
    po[(size_t)(r0 + r) * KY + n]      = a0[r];
    po[(size_t)(16 + r0 + r) * KY + n] = a1[r];
    po[(size_t)(32 + r0 + r) * KY + n] = a2[r];
    po[(size_t)(48 + r0 + r) * KY + n] = a3[r];
  }
}

// ---------------- K6 legacy (slow path, bias fused) ----------------
__global__ __launch_bounds__(256) void k6_lsm_mfma(
    const unsigned short* __restrict__ xb, const float* __restrict__ W,
    const float* __restrict__ bias, float* __restrict__ out) {
  int tid = threadIdx.x;
  int wv = tid >> 6, lane = tid & 63;
  int n = blockIdx.x * 64 + wv * 16 + (lane & 15);
  int kg = lane >> 4;
  const float* wp = W + (size_t)n * H3 + kg * 8;
  const unsigned short* xp = xb + (size_t)(lane & 15) * H3 + kg * 8;
  f32x4 a0 = {0.f, 0.f, 0.f, 0.f}, a1 = a0, a2 = a0, a3 = a0;
  #pragma unroll 2
  for (int k0 = 0; k0 < H3; k0 += 32) {
    float4 wlo = *(const float4*)(wp + k0);
    float4 whi = *(const float4*)(wp + k0 + 4);
    u16x8 bu;
    bu[0] = f2bf(wlo.x); bu[1] = f2bf(wlo.y); bu[2] = f2bf(wlo.z); bu[3] = f2bf(wlo.w);
    bu[4] = f2bf(whi.x); bu[5] = f2bf(whi.y); bu[6] = f2bf(whi.z); bu[7] = f2bf(whi.w);
    bf16x8 bf = __builtin_bit_cast(bf16x8, bu);
    u16x8 x0 = *(const u16x8*)(xp + k0);
    u16x8 x1 = *(const u16x8*)(xp + 16 * H3 + k0);
    u16x8 x2 = *(const u16x8*)(xp + 32 * H3 + k0);
    u16x8 x3 = *(const u16x8*)(xp + 48 * H3 + k0);
    a0 = __builtin_amdgcn_mfma_f32_16x16x32_bf16(__builtin_bit_cast(bf16x8, x0), bf, a0, 0, 0, 0);
    a1 = __builtin_amdgcn_mfma_f32_16x16x32_bf16(__builtin_bit_cast(bf16x8, x1), bf, a1, 0, 0, 0);
    a2 = __builtin_amdgcn_mfma_f32_16x16x32_bf16(__builtin_bit_cast(bf16x8, x2), bf, a2, 0, 0, 0);
    a3 = __builtin_amdgcn_mfma_f32_16x16x32_bf16(__builtin_bit_cast(bf16x8, x3), bf, a3, 0, 0, 0);
  }
  float bv = bias[n];
  int r0 = kg * 4;
  #pragma unroll
  for (int r = 0; r < 4; ++r) {
    out[(size_t)(r0 + r) * KY + n]      = a0[r] + bv;
    out[(size_t)(16 + r0 + r) * KY + n] = a1[r] + bv;
    out[(size_t)(32 + r0 + r) * KY + n] = a2[r] + bv;
    out[(size_t)(48 + r0 + r) * KY + n] = a3[r] + bv;
  }
}

// ---------------- K7a: logits = part0+part1+bias; per-(b,quarter) max & sumexp ----------------
__global__ __launch_bounds__(256) void k7a(const float* __restrict__ part,
                                           const float* __restrict__ bias,
                                           float* __restrict__ out,
                                           float* __restrict__ pm, float* __restrict__ ps) {
  int b = blockIdx.y, q = blockIdx.x;       // q in [0,4)
  const float* p0 = part + (size_t)b * KY;
  const float* p1 = part + (size_t)B_ * KY + (size_t)b * KY;
  float* orow = out + (size_t)b * KY;
  int base = q * (KY / 4);
  int end  = base + (KY / 4);
  float mx = -1e30f;
  for (int k = base + threadIdx.x; k < end; k += 256) {
    float v = p0[k] + p1[k] + bias[k];
    orow[k] = v;
    mx = fmaxf(mx, v);
  }
  __shared__ float sm[256];
  sm[threadIdx.x] = mx; __syncthreads();
  for (int off = 128; off; off >>= 1) {
    if (threadIdx.x < off) sm[threadIdx.x] = fmaxf(sm[threadIdx.x], sm[threadIdx.x + off]);
    __syncthreads();
  }
  float M = sm[0]; __syncthreads();
  float s = 0.f;
  for (int k = base + threadIdx.x; k < end; k += 256)
    s += expf(orow[k] - M);
  sm[threadIdx.x] = s; __syncthreads();
  for (int off = 128; off; off >>= 1) {
    if (threadIdx.x < off) sm[threadIdx.x] += sm[threadIdx.x + off];
    __syncthreads();
  }
  if (threadIdx.x == 0) { pm[b * 4 + q] = M; ps[b * 4 + q] = sm[0]; }
}

// ---------------- K7b: combine partial (max,sumexp) -> lse ----------------
__global__ void k7b(const float* __restrict__ pm, const float* __restrict__ ps,
                    float* __restrict__ lse) {
  int b = threadIdx.x;  // 64
  float m0 = pm[b*4], m1 = pm[b*4+1], m2 = pm[b*4+2], m3 = pm[b*4+3];
  float M = fmaxf(fmaxf(m0, m1), fmaxf(m2, m3));
  float s = ps[b*4]   * expf(m0 - M) + ps[b*4+1] * expf(m1 - M)
          + ps[b*4+2] * expf(m2 - M) + ps[b*4+3] * expf(m3 - M);
  lse[b] = M + logf(s);
}

// ---------------- K7 legacy (slow path) ----------------
__global__ void k7_lse(const float* __restrict__ logits, float* __restrict__ lse) {
  int b = blockIdx.x;
  const float* row = logits + (size_t)b * KY;
  __shared__ float sm[256];
  float mx = -1e30f;
  for (int k = threadIdx.x; k < KY; k += 256) mx = fmaxf(mx, row[k]);
  sm[threadIdx.x] = mx; __syncthreads();
  for (int off = 128; off; off >>= 1) {
    if (threadIdx.x < off) sm[threadIdx.x] = fmaxf(sm[threadIdx.x], sm[threadIdx.x + off]);
    __syncthreads();
  }
  mx = sm[0]; __syncthreads();
  float s = 0.f;
  for (int k = threadIdx.x; k < KY; k += 256) s += expf(row[k] - mx);
  sm[threadIdx.x] = s; __syncthreads();
  for (int off = 128; off; off >>= 1) {
    if (threadIdx.x < off) sm[threadIdx.x] += sm[threadIdx.x + off];
    __syncthreads();
  }
  if (threadIdx.x == 0) lse[b] = mx + logf(sm[0]);
}

// ---------------- K8: in-place out = logits - lse ----------------
__global__ void k8_out(float* __restrict__ outp, const float* __restrict__ lse) {
  int b = blockIdx.y;
  int k = blockIdx.x * 256 + threadIdx.x;
  size_t idx = (size_t)b * KY + k;
  outp[idx] = outp[idx] - lse[b];
}

extern "C" void kernel_launch(void* const* d_in, const int* in_sizes, int n_in,
                              void* d_out, int out_size, void* d_ws, size_t ws_size,
                              hipStream_t stream) {
  const int*   input  = (const int*)  d_in[0];
  const float* hidden = (const float*)d_in[1];
  const float* enc    = (const float*)d_in[2];
  const float* emb_W  = (const float*)d_in[3];
  const float* Wih    = (const float*)d_in[4];
  const float* Whh    = (const float*)d_in[5];
  const float* bih    = (const float*)d_in[6];
  const float* bhh    = (const float*)d_in[7];
  const float* lsm_W  = (const float*)d_in[8];
  const float* lsm_b  = (const float*)d_in[9];
  const float* aW1    = (const float*)d_in[10];
  const float* ab1    = (const float*)d_in[11];
  const float* aW2    = (const float*)d_in[12];
  const float* ab2    = (const float*)d_in[13];

  float* out   = (float*)d_out;           // log_softmax output (logits in place first)
  float* hnew  = out + (size_t)B_ * KY;   // h_new

  int gis = 5, ghs = 2;
  // fast-path f32 scratch: hpart..part
  size_t base_fast = 65536 + 131072 + 8192 + 131072 + 163840
                   + (size_t)gis * 196608 + (size_t)ghs * 196608
                   + 98304 + 64 + 256 + 256 + (size_t)2 * B_ * KY;
  size_t need_fast = (base_fast + 8388608 + 1048576) * 4;  // + encb/w1b (bf16 as f32-equiv)
  int fast = (ws_size >= need_fast);
  if (!fast) {
    size_t base_slow = 65536 + 131072 + 8192 + 131072 + 163840
                     + (size_t)gis * 196608 + (size_t)ghs * 196608 + 98304 + 64;
    if (ws_size < base_slow * 4) { gis = 1; ghs = 1; }
  }

  float* ws = (float*)d_ws;
  unsigned short* encb = (unsigned short*)ws;                 // 32 MB bf16 (fast only)
  unsigned short* w1b  = encb + (fast ? 16777216 : 0);        // 4 MB bf16 (fast only)
  float* fbase = fast ? (float*)(w1b + 2097152) : ws;
  float* hpart     = fbase;
  float* scorepart = hpart + 65536;
  float* w         = scorepart + 131072;
  float* context   = w + 8192;
  float* rnn_in    = context + 131072;
  float* gi        = rnn_in + 163840;
  float* gh        = gi + (size_t)gis * 196608;
  unsigned short* xb = (unsigned short*)(gh + (size_t)ghs * 196608);
  float* lse       = (float*)(xb + 196608);
  float* pm        = lse + 64;
  float* ps        = pm + 256;
  float* part      = ps + 256;            // 2*64*32000 f32 (fast only)

  k1_hpart<<<dim3(256, 64), 256, 0, stream>>>(hidden, aW1, ab1, hpart);
  if (fast) {
    kc_all<<<9216, 256, 0, stream>>>(enc, aW1, encb, w1b);
    k2_mfma<<<512, 256, 0, stream>>>(encb, w1b, hpart, aW2, scorepart);
    k3_softmax<<<B_, TX, 0, stream>>>(scorepart, ab2, w, 8);
    k4_context_bf<<<dim3(4, B_), 256, 0, stream>>>(encb, w, context);
    k5a_rnnin<<<B_, 256, 0, stream>>>(input, emb_W, context, rnn_in);
    k_gates_gemm<<<dim3(H3 / 64, 7), 256, 0, stream>>>(rnn_in, Wih, bih, hidden, Whh, bhh, gi, gh);
    k5c_gates<<<B_, 256, 0, stream>>>(gi, gh, gis, ghs, hidden, context, hnew, xb);
    k6_split<<<dim3(KY / 64, 2), 256, 0, stream>>>(xb, lsm_W, part);
    k7a<<<dim3(4, B_), 256, 0, stream>>>(part, lsm_b, out, pm, ps);
    k7b<<<1, 64, 0, stream>>>(pm, ps, lse);
  } else {
    k2_gemm_score<<<dim3(M_ / 64, 16), 256, 0, stream>>>(enc, aW1, hpart, aW2, scorepart);
    k3_softmax<<<B_, TX, 0, stream>>>(scorepart, ab2, w, 16);
    k4_context<<<dim3(H2 / 256, B_), 256, 0, stream>>>(enc, w, context);
    k5a_rnnin<<<B_, 256, 0, stream>>>(input, emb_W, context, rnn_in);
    k_gemm_T<<<dim3(H3 / 64, gis), 256, 0, stream>>>(rnn_in, Wih, bih, gi, H3, EC);
    k_gemm_T<<<dim3(H3 / 64, ghs), 256, 0, stream>>>(hidden, Whh, bhh, gh, H3, H_);
    k5c_gates<<<B_, 256, 0, stream>>>(gi, gh, gis, ghs, hidden, context, hnew, xb);
    k6_lsm_mfma<<<KY / 64, 256, 0, stream>>>(xb, lsm_W, lsm_b, out);
    k7_lse<<<B_, 256, 0, stream>>>(out, lse);
  }
  k8_out<<<dim3(KY / 256, B_), 256, 0, stream>>>(out, lse);
}